// Round 3
// baseline (185.879 us; speedup 1.0000x reference)
//
#include <hip/hip_runtime.h>
#include <hip/hip_bf16.h>
#include <stdint.h>

typedef uint32_t u32;
typedef uint64_t u64;
typedef __bf16 bf16x8 __attribute__((ext_vector_type(8)));
typedef float f32x4 __attribute__((ext_vector_type(4)));
typedef u32 u32x4 __attribute__((ext_vector_type(4)));

#define NB 8
#define NN 2048
#define DIN 256
#define DOUT 256
#define NR 4
#define KTOT (NN * NR)  // 8192

// ws layout
#define XW_BYTES   (NB * DOUT * KTOT * 2)          // 33,554,432
#define PART_BYTES (NB * NN * DOUT * 4)            // 16,777,216

__device__ __forceinline__ ushort f2bf(float f) {
  union { float f; u32 u; } c; c.f = f;
  return (ushort)((c.u + 0x7FFFu + ((c.u >> 16) & 1u)) >> 16);
}

__device__ __forceinline__ void gload_lds16(const void* g, void* l) {
  __builtin_amdgcn_global_load_lds(
      (const __attribute__((address_space(1))) u32*)g,
      (__attribute__((address_space(3))) u32*)l, 16, 0, 0);
}

// ---------------- kernel 0: wT[r][o][d] = bf16(w[r][d][o]) ----------------
__global__ void k0_wT(const float* __restrict__ w, ushort* __restrict__ wT) {
  int i = blockIdx.x * 256 + threadIdx.x;   // 262144 total
  int o = i & 255, d = (i >> 8) & 255, r = i >> 16;
  wT[(r * DOUT + o) * DIN + d] = f2bf(w[i]);
}

// ---------------- kernel 1: xwT[b][o][m*4+r] = bf16(x[b,m,:]@W[r][:,o]) ----
__global__ __launch_bounds__(512) void k1_xw(const float* __restrict__ x,
                                             const ushort* __restrict__ wT,
                                             ushort* __restrict__ xwT) {
  __shared__ char smem[65536];
  ushort* As = (ushort*)smem;           // [64 m][32 d]
  ushort* Bs = (ushort*)(smem + 4096);  // [4 r][128 o][32 d]
  const int t = threadIdx.x, l = t & 63, w = t >> 6;
  const int r = w >> 1, oh = w & 1;
  const int blk = blockIdx.x;
  const int b = blk >> 6, rest = blk & 63, mc = rest >> 1, ot = rest & 1;

  f32x4 acc[4][4] = {};
  const int arow = t >> 3, adc = (t & 7) << 2;
  const float* xg = x + ((size_t)(b * NN + mc * 64 + arow) * DIN + adc);

  for (int s = 0; s < 8; ++s) {
    const int d0 = s * 32;
    float4 xv = *(const float4*)(xg + d0);
    ushort4 a4;
    a4.x = f2bf(xv.x); a4.y = f2bf(xv.y); a4.z = f2bf(xv.z); a4.w = f2bf(xv.w);
    *(ushort4*)(As + arow * 32 + adc) = a4;
#pragma unroll
    for (int i = 0; i < 4; ++i) {
      int off = i * 4096 + t * 8;
      int rr = off >> 12, rem = off & 4095, o = rem >> 5, dd = rem & 31;
      const ushort* src = wT + ((size_t)(rr * DOUT + ot * 128 + o) * DIN + d0 + dd);
      gload_lds16(src, Bs + off);
    }
    __syncthreads();
    bf16x8 af[4];
#pragma unroll
    for (int fm = 0; fm < 4; ++fm)
      af[fm] = *(const bf16x8*)(As + (fm * 16 + (l & 15)) * 32 + (l >> 4) * 8);
#pragma unroll
    for (int fo = 0; fo < 4; ++fo) {
      bf16x8 bf = *(const bf16x8*)(Bs + (size_t)(r * 128 + oh * 64 + fo * 16 + (l & 15)) * 32 + (l >> 4) * 8);
#pragma unroll
      for (int fm = 0; fm < 4; ++fm)
        acc[fm][fo] = __builtin_amdgcn_mfma_f32_16x16x32_bf16(af[fm], bf, acc[fm][fo], 0, 0, 0);
    }
    __syncthreads();
  }
  ushort* Cs = (ushort*)smem;
#pragma unroll
  for (int fm = 0; fm < 4; ++fm)
#pragma unroll
    for (int fo = 0; fo < 4; ++fo)
#pragma unroll
      for (int j = 0; j < 4; ++j) {
        int o_loc = oh * 64 + fo * 16 + (l & 15);
        int ml = fm * 16 + (l >> 4) * 4 + j;
        Cs[o_loc * 256 + ml * 4 + r] = f2bf(acc[fm][fo][j]);
      }
  __syncthreads();
#pragma unroll
  for (int i = 0; i < 8; ++i) {
    int el = (i * 512 + t) * 8;
    int o_loc = el >> 8, kp = el & 255;
    *(uint4*)(xwT + (size_t)(b * DOUT + ot * 128 + o_loc) * KTOT + mc * 256 + kp) =
        *(const uint4*)(Cs + el);
  }
}

// ---------------- kernel 2: one-hot GEMM, depth-2 counted-vmcnt pipeline ---
// grid 512 logical: b.nt.ks.ot, XCD-swizzled so ot-pairs co-XCD.
// 256 thr = 4 waves (2x2), wave 64x64, 4x4 frags 16x16x32, BK=64.
// LDS 64KB: A dbuf 2x16KB (reg rel->one-hot, XOR-swz) + B dbuf 2x16KB
// (global->reg->ds_write XOR-swz). Raw s_barrier + lgkmcnt(0) only —
// B/rel loads for s+2 stay in flight across the barrier (T4).
__global__ __launch_bounds__(256, 2) void k2_main(const int* __restrict__ rel,
                                                  const ushort* __restrict__ xwT,
                                                  float* __restrict__ out,
                                                  float* __restrict__ part) {
  __shared__ char smem[65536];
  const int t = threadIdx.x, l = t & 63, w = t >> 6;
  const int wr = w >> 1, wc = w & 1;
  const int logical = (blockIdx.x & 7) * 64 + (blockIdx.x >> 3);
  const int b = logical >> 6;
  const int nt = (logical >> 2) & 15;
  const int ks = (logical >> 1) & 1;
  const int ot = logical & 1;

  f32x4 acc[4][4] = {};
  const int arow = t >> 1, half = t & 1;
  const int* relg = rel + ((size_t)(b * NN + nt * 128 + arow) * NN + ks * 1024 + half * 8);
  const ushort* xwb = xwT + (size_t)(b * DOUT + ot * 128) * KTOT + ks * 4096;

  char* const Ab0 = smem;
  char* const Ab1 = smem + 16384;
  char* const Bb0 = smem + 32768;
  char* const Bb1 = smem + 49152;

  // B staging geometry: thread t owns rows o = (t>>3) + 32*i, 16B chunk (t&7)
  const int brow = t >> 3;
  const int bcol = (t & 7) * 8;                                   // elem
  const int bwcol = ((t & 7) * 16) ^ (((t >> 3) & 7) << 4);       // byte, swz
  const int aswz = (arow & 7) << 4;
  const int fr = l & 15, fq = l >> 4;
  const int rswz = (fr & 7) << 4;

  uint4 bs0[4], bs1[4];
  int4 rs0a, rs0b, rs1a, rs1b;

#define EXPAND_A(ABASE, V0, V1)                                                \
  {                                                                            \
    char* rowp = (ABASE) + arow * 128;                                         \
    int vv[8] = {V0.x, V0.y, V0.z, V0.w, V1.x, V1.y, V1.z, V1.w};              \
    _Pragma("unroll") for (int p = 0; p < 4; ++p) {                            \
      int va = vv[2 * p], vb = vv[2 * p + 1];                                  \
      u32 sa = ((u32)(va - 1) & 3u) * 16u;                                     \
      u32 sb = ((u32)(vb - 1) & 3u) * 16u;                                     \
      u64 ha = va ? (0x3F80ull << sa) : 0ull;                                  \
      u64 hb = vb ? (0x3F80ull << sb) : 0ull;                                  \
      u32x4 e = {(u32)ha, (u32)(ha >> 32), (u32)hb, (u32)(hb >> 32)};          \
      *(u32x4*)(rowp + ((half * 64 + p * 16) ^ aswz)) = e;                     \
    }                                                                          \
  }

#define LOAD_B(SET, S)                                                         \
  _Pragma("unroll") for (int i = 0; i < 4; ++i)                                \
    SET[i] = *(const uint4*)(xwb + (size_t)(brow + 32 * i) * KTOT + (S) * 64 + bcol);

#define WRITE_B(BBASE, SET)                                                    \
  _Pragma("unroll") for (int i = 0; i < 4; ++i)                                \
    *(uint4*)((BBASE) + (brow + 32 * i) * 128 + bwcol) = SET[i];

#define BAR()                                                                  \
  asm volatile("s_waitcnt lgkmcnt(0)" ::: "memory");                           \
  __builtin_amdgcn_s_barrier();                                                \
  __builtin_amdgcn_sched_barrier(0);

#define MFMA_STEP(AC, BC)                                                      \
  __builtin_amdgcn_s_setprio(1);                                               \
  _Pragma("unroll") for (int kk = 0; kk < 2; ++kk) {                           \
    bf16x8 af[4], bfv[4];                                                      \
    const int colb = (kk * 64 + fq * 16) ^ rswz;                               \
    _Pragma("unroll") for (int fm = 0; fm < 4; ++fm)                           \
      af[fm] = *(const bf16x8*)((AC) + (wr * 64 + fm * 16 + fr) * 128 + colb); \
    _Pragma("unroll") for (int fo = 0; fo < 4; ++fo)                           \
      bfv[fo] = *(const bf16x8*)((BC) + (wc * 64 + fo * 16 + fr) * 128 + colb);\
    _Pragma("unroll") for (int fm = 0; fm < 4; ++fm)                           \
      _Pragma("unroll") for (int fo = 0; fo < 4; ++fo)                         \
        acc[fm][fo] = __builtin_amdgcn_mfma_f32_16x16x32_bf16(                 \
            af[fm], bfv[fo], acc[fm][fo], 0, 0, 0);                            \
  }                                                                            \
  __builtin_amdgcn_s_setprio(0);

#define BODY(S, P, Q)                                                          \
  {                                                                            \
    if ((S) < 62) {                                                            \
      LOAD_B(bs##P, (S) + 2);                                                  \
      rs##P##a = *(const int4*)(relg + ((S) + 2) * 16);                        \
      rs##P##b = *(const int4*)(relg + ((S) + 2) * 16 + 4);                    \
    }                                                                          \
    MFMA_STEP(Ab##P, Bb##P);                                                   \
    if ((S) < 63) {                                                            \
      WRITE_B(Bb##Q, bs##Q);                                                   \
      EXPAND_A(Ab##Q, rs##Q##a, rs##Q##b);                                     \
    }                                                                          \
    BAR();                                                                     \
  }

  // prologue: prime step 0 (LDS) and step 1 (registers)
  LOAD_B(bs0, 0);
  rs0a = *(const int4*)(relg);
  rs0b = *(const int4*)(relg + 4);
  LOAD_B(bs1, 1);
  rs1a = *(const int4*)(relg + 16);
  rs1b = *(const int4*)(relg + 20);
  WRITE_B(Bb0, bs0);
  EXPAND_A(Ab0, rs0a, rs0b);
  BAR();

  for (int s = 0; s < 64; s += 2) {
    BODY(s, 0, 1);
    BODY(s + 1, 1, 0);
  }

  float* dst = ks ? part : out;
#pragma unroll
  for (int fm = 0; fm < 4; ++fm)
#pragma unroll
    for (int fo = 0; fo < 4; ++fo) {
      int n = nt * 128 + wr * 64 + fm * 16 + fq * 4;
      int o = ot * 128 + wc * 64 + fo * 16 + fr;
#pragma unroll
      for (int j = 0; j < 4; ++j)
        dst[(size_t)(b * NN + n + j) * DOUT + o] = acc[fm][fo][j];
    }
#undef BODY
#undef MFMA_STEP
#undef BAR
#undef WRITE_B
#undef LOAD_B
#undef EXPAND_A
}

// ---------------- kernel 3: out = out(ks0) + part(ks1) + bias --------------
__global__ void k3_add(float* __restrict__ out, const float* __restrict__ part,
                       const float* __restrict__ bias) {
  int i = blockIdx.x * 256 + threadIdx.x;  // float4 index, 1048576 total
  float4 o = ((const float4*)out)[i];
  float4 p = ((const float4*)part)[i];
  float4 bv = ((const float4*)bias)[i & 63];
  float4 rr;
  rr.x = o.x + p.x + bv.x;
  rr.y = o.y + p.y + bv.y;
  rr.z = o.z + p.z + bv.z;
  rr.w = o.w + p.w + bv.w;
  ((float4*)out)[i] = rr;
}

extern "C" void kernel_launch(void* const* d_in, const int* in_sizes, int n_in,
                              void* d_out, int out_size, void* d_ws, size_t ws_size,
                              hipStream_t stream) {
  const float* x = (const float*)d_in[0];
  const int* rel = (const int*)d_in[2];
  const float* wgt = (const float*)d_in[3];
  const float* bias = (const float*)d_in[4];
  float* out = (float*)d_out;
  char* ws = (char*)d_ws;

  ushort* xwT = (ushort*)ws;                                 // 32 MiB
  float* part = (float*)(ws + XW_BYTES);                     // 16 MiB
  ushort* wT = (ushort*)(ws + XW_BYTES + PART_BYTES);        // 0.5 MiB

  k0_wT<<<1024, 256, 0, stream>>>(wgt, wT);
  k1_xw<<<512, 512, 0, stream>>>(x, wT, xwT);
  k2_main<<<512, 256, 0, stream>>>(rel, xwT, out, part);
  k3_add<<<4096, 256, 0, stream>>>(out, part, bias);
}

// Round 4
// 118.044 us; speedup vs baseline: 1.5747x; 1.5747x over previous
//
#include <hip/hip_runtime.h>
#include <hip/hip_bf16.h>
#include <stdint.h>

typedef uint32_t u32;
typedef uint64_t u64;
typedef __bf16 bf16x8 __attribute__((ext_vector_type(8)));
typedef float f32x4 __attribute__((ext_vector_type(4)));
typedef u32 u32x4 __attribute__((ext_vector_type(4)));

#define NB 8
#define NN 2048
#define DIN 256
#define DOUT 256
#define NR 4
#define KTOT (NN * NR)  // 8192

// ws layout
#define XW_BYTES   (NB * DOUT * KTOT * 2)          // 33,554,432
#define PART_BYTES (NB * NN * DOUT * 4)            // 16,777,216

__device__ __forceinline__ ushort f2bf(float f) {
  union { float f; u32 u; } c; c.f = f;
  return (ushort)((c.u + 0x7FFFu + ((c.u >> 16) & 1u)) >> 16);
}

__device__ __forceinline__ void gload_lds16(const void* g, void* l) {
  __builtin_amdgcn_global_load_lds(
      (const __attribute__((address_space(1))) u32*)g,
      (__attribute__((address_space(3))) u32*)l, 16, 0, 0);
}

// ---------------- kernel 0: wT[r][o][d] = bf16(w[r][d][o]) ----------------
__global__ void k0_wT(const float* __restrict__ w, ushort* __restrict__ wT) {
  int i = blockIdx.x * 256 + threadIdx.x;   // 262144 total
  int o = i & 255, d = (i >> 8) & 255, r = i >> 16;
  wT[(r * DOUT + o) * DIN + d] = f2bf(w[i]);
}

// ---------------- kernel 1: xwT[b][o][m*4+r] = bf16(x[b,m,:]@W[r][:,o]) ----
__global__ __launch_bounds__(512) void k1_xw(const float* __restrict__ x,
                                             const ushort* __restrict__ wT,
                                             ushort* __restrict__ xwT) {
  __shared__ char smem[65536];
  ushort* As = (ushort*)smem;           // [64 m][32 d]
  ushort* Bs = (ushort*)(smem + 4096);  // [4 r][128 o][32 d]
  const int t = threadIdx.x, l = t & 63, w = t >> 6;
  const int r = w >> 1, oh = w & 1;
  const int blk = blockIdx.x;
  const int b = blk >> 6, rest = blk & 63, mc = rest >> 1, ot = rest & 1;

  f32x4 acc[4][4] = {};
  const int arow = t >> 3, adc = (t & 7) << 2;
  const float* xg = x + ((size_t)(b * NN + mc * 64 + arow) * DIN + adc);

  for (int s = 0; s < 8; ++s) {
    const int d0 = s * 32;
    float4 xv = *(const float4*)(xg + d0);
    ushort4 a4;
    a4.x = f2bf(xv.x); a4.y = f2bf(xv.y); a4.z = f2bf(xv.z); a4.w = f2bf(xv.w);
    *(ushort4*)(As + arow * 32 + adc) = a4;
#pragma unroll
    for (int i = 0; i < 4; ++i) {
      int off = i * 4096 + t * 8;
      int rr = off >> 12, rem = off & 4095, o = rem >> 5, dd = rem & 31;
      const ushort* src = wT + ((size_t)(rr * DOUT + ot * 128 + o) * DIN + d0 + dd);
      gload_lds16(src, Bs + off);
    }
    __syncthreads();
    bf16x8 af[4];
#pragma unroll
    for (int fm = 0; fm < 4; ++fm)
      af[fm] = *(const bf16x8*)(As + (fm * 16 + (l & 15)) * 32 + (l >> 4) * 8);
#pragma unroll
    for (int fo = 0; fo < 4; ++fo) {
      bf16x8 bf = *(const bf16x8*)(Bs + (size_t)(r * 128 + oh * 64 + fo * 16 + (l & 15)) * 32 + (l >> 4) * 8);
#pragma unroll
      for (int fm = 0; fm < 4; ++fm)
        acc[fm][fo] = __builtin_amdgcn_mfma_f32_16x16x32_bf16(af[fm], bf, acc[fm][fo], 0, 0, 0);
    }
    __syncthreads();
  }
  ushort* Cs = (ushort*)smem;
#pragma unroll
  for (int fm = 0; fm < 4; ++fm)
#pragma unroll
    for (int fo = 0; fo < 4; ++fo)
#pragma unroll
      for (int j = 0; j < 4; ++j) {
        int o_loc = oh * 64 + fo * 16 + (l & 15);
        int ml = fm * 16 + (l >> 4) * 4 + j;
        Cs[o_loc * 256 + ml * 4 + r] = f2bf(acc[fm][fo][j]);
      }
  __syncthreads();
#pragma unroll
  for (int i = 0; i < 8; ++i) {
    int el = (i * 512 + t) * 8;
    int o_loc = el >> 8, kp = el & 255;
    *(uint4*)(xwT + (size_t)(b * DOUT + ot * 128 + o_loc) * KTOT + mc * 256 + kp) =
        *(const uint4*)(Cs + el);
  }
}

// ---------------- kernel 2: one-hot GEMM, depth-2 counted-vmcnt pipeline ---
// grid 512 logical: b.nt.ks.ot, XCD-swizzled so each XCD owns one b.
// 256 thr = 4 waves (2x2), wave 64x64, 4x4 frags 16x16x32, BK=64.
// LDS 80KB: A dbuf 2x16KB (VALU one-hot expand, XOR-swz) + B 3-buf 3x16KB
// (global_load_lds, source-preswizzled). Stage s+2 while computing s;
// barrier = s_waitcnt vmcnt(6) + s_barrier: the 6 newest vm ops
// (B(s+2)x4 + rel(s+2)x2) stay in flight across the barrier (T4).
// In-order vmcnt retire => B(s+1)+rel(s+1) complete at the barrier.
__global__ __launch_bounds__(256, 2) void k2_main(const int* __restrict__ rel,
                                                  const ushort* __restrict__ xwT,
                                                  float* __restrict__ out,
                                                  float* __restrict__ part) {
  __shared__ char smem[81920];
  const int t = threadIdx.x, l = t & 63, w = t >> 6;
  const int wr = w >> 1, wc = w & 1;
  const int logical = (blockIdx.x & 7) * 64 + (blockIdx.x >> 3);
  const int b = logical >> 6;
  const int nt = (logical >> 2) & 15;
  const int ks = (logical >> 1) & 1;
  const int ot = logical & 1;

  f32x4 acc[4][4] = {};
  const int arow = t >> 1, half = t & 1;
  const int* relg = rel + ((size_t)(b * NN + nt * 128 + arow) * NN + ks * 1024 + half * 8);
  const ushort* xwb = xwT + (size_t)(b * DOUT + ot * 128) * KTOT + ks * 4096;

  char* const Ab0 = smem;
  char* const Ab1 = smem + 16384;
  char* const Bb0 = smem + 32768;
  char* const Bb1 = smem + 49152;
  char* const Bb2 = smem + 65536;

  // B staging: thread t owns rows o=(t>>3)+32*i, source col pre-swizzled (#21)
  const int brow = t >> 3;
  const int kd = (((t & 7) ^ ((t >> 3) & 7)) << 3);  // elem offset, swz
  const int aswz = (arow & 7) << 4;
  const int fr = l & 15, fq = l >> 4;
  const int rswz = (fr & 7) << 4;

  int4 rsA0, rsB0, rsA1, rsB1;  // rel prefetch, set = target-step parity

#define STAGE_B(S, BBASE)                                                      \
  {                                                                            \
    _Pragma("unroll") for (int i = 0; i < 4; ++i)                              \
      gload_lds16(xwb + (size_t)(brow + 32 * i) * KTOT + (S) * 64 + kd,        \
                  (BBASE) + i * 4096 + t * 16);                                \
  }

#define RELLOAD(S, RA, RB)                                                     \
  RA = *(const int4*)(relg + (S) * 16);                                        \
  RB = *(const int4*)(relg + (S) * 16 + 4);

#define EXPAND_A(ABASE, V0, V1)                                                \
  {                                                                            \
    char* rowp = (ABASE) + arow * 128;                                         \
    int vv[8] = {V0.x, V0.y, V0.z, V0.w, V1.x, V1.y, V1.z, V1.w};              \
    _Pragma("unroll") for (int p = 0; p < 4; ++p) {                            \
      int va = vv[2 * p], vb = vv[2 * p + 1];                                  \
      u32 sa = ((u32)(va - 1) & 3u) * 16u;                                     \
      u32 sb = ((u32)(vb - 1) & 3u) * 16u;                                     \
      u64 ha = va ? (0x3F80ull << sa) : 0ull;                                  \
      u64 hb = vb ? (0x3F80ull << sb) : 0ull;                                  \
      u32x4 e = {(u32)ha, (u32)(ha >> 32), (u32)hb, (u32)(hb >> 32)};          \
      *(u32x4*)(rowp + ((half * 64 + p * 16) ^ aswz)) = e;                     \
    }                                                                          \
  }

#define BARV6()                                                                \
  asm volatile("s_waitcnt vmcnt(6) lgkmcnt(0)" ::: "memory");                  \
  __builtin_amdgcn_s_barrier();                                                \
  __builtin_amdgcn_sched_barrier(0);

#define BARV0()                                                                \
  asm volatile("s_waitcnt vmcnt(0) lgkmcnt(0)" ::: "memory");                  \
  __builtin_amdgcn_s_barrier();                                                \
  __builtin_amdgcn_sched_barrier(0);

#define MFMA_STEP(AC, BC)                                                      \
  __builtin_amdgcn_s_setprio(1);                                               \
  _Pragma("unroll") for (int kk = 0; kk < 2; ++kk) {                           \
    bf16x8 af[4], bfv[4];                                                      \
    const int colb = (kk * 64 + fq * 16) ^ rswz;                               \
    _Pragma("unroll") for (int fm = 0; fm < 4; ++fm)                           \
      af[fm] = *(const bf16x8*)((AC) + (wr * 64 + fm * 16 + fr) * 128 + colb); \
    _Pragma("unroll") for (int fo = 0; fo < 4; ++fo)                           \
      bfv[fo] = *(const bf16x8*)((BC) + (wc * 64 + fo * 16 + fr) * 128 + colb);\
    _Pragma("unroll") for (int fm = 0; fm < 4; ++fm)                           \
      _Pragma("unroll") for (int fo = 0; fo < 4; ++fo)                         \
        acc[fm][fo] = __builtin_amdgcn_mfma_f32_16x16x32_bf16(                 \
            af[fm], bfv[fo], acc[fm][fo], 0, 0, 0);                            \
  }                                                                            \
  __builtin_amdgcn_s_setprio(0);

// full body: stage B(S+2)+rel(S+2), compute S, expand A(S+1), counted barrier
#define BODY(S, ACUR, BCUR, ANXT, RLA, RLB, RCA, RCB, BSTG)                    \
  {                                                                            \
    STAGE_B((S) + 2, BSTG);                                                    \
    RELLOAD((S) + 2, RLA, RLB);                                                \
    MFMA_STEP(ACUR, BCUR);                                                     \
    EXPAND_A(ANXT, RCA, RCB);                                                  \
    BARV6();                                                                   \
  }

  // prologue: prime steps 0 (LDS) and 1 (in flight)
  STAGE_B(0, Bb0);
  RELLOAD(0, rsA0, rsB0);
  STAGE_B(1, Bb1);
  RELLOAD(1, rsA1, rsB1);
  EXPAND_A(Ab0, rsA0, rsB0);   // compiler auto-waits rel(0) regs
  BARV6();                     // B(0) guaranteed resident (oldest 6 retired)

  for (int s = 0; s < 60; s += 6) {
    BODY(s + 0, Ab0, Bb0, Ab1, rsA0, rsB0, rsA1, rsB1, Bb2);
    BODY(s + 1, Ab1, Bb1, Ab0, rsA1, rsB1, rsA0, rsB0, Bb0);
    BODY(s + 2, Ab0, Bb2, Ab1, rsA0, rsB0, rsA1, rsB1, Bb1);
    BODY(s + 3, Ab1, Bb0, Ab0, rsA1, rsB1, rsA0, rsB0, Bb2);
    BODY(s + 4, Ab0, Bb1, Ab1, rsA0, rsB0, rsA1, rsB1, Bb0);
    BODY(s + 5, Ab1, Bb2, Ab0, rsA1, rsB1, rsA0, rsB0, Bb1);
  }
  // tail: s = 60..63
  BODY(60, Ab0, Bb0, Ab1, rsA0, rsB0, rsA1, rsB1, Bb2);
  BODY(61, Ab1, Bb1, Ab0, rsA1, rsB1, rsA0, rsB0, Bb0);
  {  // s = 62: no stage; need rel(63)+B(63) fully landed -> vmcnt(0)
    MFMA_STEP(Ab0, Bb2);
    EXPAND_A(Ab1, rsA1, rsB1);
    BARV0();
  }
  {  // s = 63: final compute
    MFMA_STEP(Ab1, Bb0);
  }

  float* dst = ks ? part : out;
#pragma unroll
  for (int fm = 0; fm < 4; ++fm)
#pragma unroll
    for (int fo = 0; fo < 4; ++fo) {
      int n = nt * 128 + wr * 64 + fm * 16 + fq * 4;
      int o = ot * 128 + wc * 64 + fo * 16 + fr;
#pragma unroll
      for (int j = 0; j < 4; ++j)
        dst[(size_t)(b * NN + n + j) * DOUT + o] = acc[fm][fo][j];
    }
#undef BODY
#undef MFMA_STEP
#undef BARV6
#undef BARV0
#undef EXPAND_A
#undef RELLOAD
#undef STAGE_B
}

// ---------------- kernel 3: out = out(ks0) + part(ks1) + bias --------------
__global__ void k3_add(float* __restrict__ out, const float* __restrict__ part,
                       const float* __restrict__ bias) {
  int i = blockIdx.x * 256 + threadIdx.x;  // float4 index, 1048576 total
  float4 o = ((const float4*)out)[i];
  float4 p = ((const float4*)part)[i];
  float4 bv = ((const float4*)bias)[i & 63];
  float4 rr;
  rr.x = o.x + p.x + bv.x;
  rr.y = o.y + p.y + bv.y;
  rr.z = o.z + p.z + bv.z;
  rr.w = o.w + p.w + bv.w;
  ((float4*)out)[i] = rr;
}

extern "C" void kernel_launch(void* const* d_in, const int* in_sizes, int n_in,
                              void* d_out, int out_size, void* d_ws, size_t ws_size,
                              hipStream_t stream) {
  const float* x = (const float*)d_in[0];
  const int* rel = (const int*)d_in[2];
  const float* wgt = (const float*)d_in[3];
  const float* bias = (const float*)d_in[4];
  float* out = (float*)d_out;
  char* ws = (char*)d_ws;

  ushort* xwT = (ushort*)ws;                                 // 32 MiB
  float* part = (float*)(ws + XW_BYTES);                     // 16 MiB
  ushort* wT = (ushort*)(ws + XW_BYTES + PART_BYTES);        // 0.5 MiB

  k0_wT<<<1024, 256, 0, stream>>>(wgt, wT);
  k1_xw<<<512, 512, 0, stream>>>(x, wT, xwT);
  k2_main<<<512, 256, 0, stream>>>(rel, xwT, out, part);
  k3_add<<<4096, 256, 0, stream>>>(out, part, bias);
}